// Round 11
// baseline (1020.789 us; speedup 1.0000x reference)
//
#include <hip/hip_runtime.h>

// VQ nearest-codebook via bf16 MFMA GEMM + exact-fp32 rescue.
// score(n,k) = 0.5*|e_k|^2 - z_n.e_k (monotone in squared distance)
//
// Round-11: block-count law (dur ~ T + 52ns*blocks, r9/r10 fit) -> halve
// blocks again: BM=512 x BN=128, TPB=1024 (16 waves), 2048 blocks, 80 KB
// LDS -> exactly 2 blocks/CU and (VGPR<=64) 32 waves/CU full occupancy.
// Per-wave geometry, staging swizzle, epilogue identical to r10 (proven).

typedef unsigned short ushort;
typedef __attribute__((ext_vector_type(8))) short short8;
typedef __attribute__((ext_vector_type(4))) float f32x4;

#define C 256
#define MTOK 16384
#define NCODE 8192
#define BM 512
#define BN 128
#define BK 64
#define TPB 1024
#define NSLAB (NCODE / BN)   // 64
#define NTILE (C / BK)       // 4
#define TROW 36              // floats per token row in epilogue table (144 B)

__device__ __forceinline__ ushort bf16_rne(float x) {
    unsigned u = __float_as_uint(x);
    return (ushort)((u + 0x7FFFu + ((u >> 16) & 1u)) >> 16);
}

__device__ __forceinline__ bool lexlt(float as, int ai, float bs, int bi) {
    return as < bs || (as == bs && ai < bi);
}

// top2 (s1,i1,s2,i2) <- top2 of {self sorted pair, other sorted pair}
__device__ __forceinline__ void merge2(float& s1, int& i1, float& s2, int& i2,
                                       float os1, int oi1, float os2, int oi2) {
    if (lexlt(os1, oi1, s1, i1)) {
        float ns2; int ni2;
        if (lexlt(s1, i1, os2, oi2)) { ns2 = s1; ni2 = i1; }
        else                         { ns2 = os2; ni2 = oi2; }
        s2 = ns2; i2 = ni2; s1 = os1; i1 = oi1;
    } else if (lexlt(os1, oi1, s2, i2)) {
        s2 = os1; i2 = oi1;
    }
}

__device__ __forceinline__ void gload_lds16(const ushort* g, ushort* l) {
    __builtin_amdgcn_global_load_lds(
        (const __attribute__((address_space(1))) unsigned int*)g,
        (__attribute__((address_space(3))) unsigned int*)l, 16, 0, 0);
}

__global__ __launch_bounds__(64) void vq_norms(const float* __restrict__ emb,
                                               float* __restrict__ hn) {
    const int k = blockIdx.x;
    const int lane = threadIdx.x;
    const float4 v = *reinterpret_cast<const float4*>(emb + (size_t)k * C + lane * 4);
    float s = v.x * v.x + v.y * v.y + v.z * v.z + v.w * v.w;
    #pragma unroll
    for (int off = 32; off; off >>= 1) s += __shfl_down(s, off);
    if (lane == 0) hn[k] = 0.5f * s;
}

__global__ __launch_bounds__(256) void vq_cast(const float* __restrict__ src,
                                               ushort* __restrict__ dst, int n4) {
    typedef __attribute__((ext_vector_type(4))) ushort us4;
    const float4* s4 = reinterpret_cast<const float4*>(src);
    us4* d4 = reinterpret_cast<us4*>(dst);
    for (int i = blockIdx.x * 256 + threadIdx.x; i < n4; i += gridDim.x * 256) {
        const float4 v = s4[i];
        us4 h;
        h[0] = bf16_rne(v.x);
        h[1] = bf16_rne(v.y);
        h[2] = bf16_rne(v.z);
        h[3] = bf16_rne(v.w);
        d4[i] = h;
    }
}

__global__ __launch_bounds__(TPB, 8) void vq_gemm(
    const ushort* __restrict__ zb, const ushort* __restrict__ eb,
    const float* __restrict__ hn, float4* __restrict__ slab) {
    __shared__ ushort smem[(BM + BN) * BK];   // 80 KB staging
    ushort* At = smem;                         // [512 rows][64 c]
    ushort* Bt = smem + BM * BK;               // [128 rows][64 c]

    const int tid = threadIdx.x;
    const int lane = tid & 63;
    const int wid = __builtin_amdgcn_readfirstlane(tid >> 6);  // 0..15
    const int wr = wid >> 1;          // 0..7 (64-token stripe)
    const int wc = wid & 1;           // 0..1 (64-code half)
    const int mbase = blockIdx.x * BM;
    const int nb = blockIdx.y;
    const int nbase = nb * BN;

    // staging: one issue = 1024 thr x 16 B = 128 rows; wave covers 8 rows
    const int srow = tid >> 3;                   // 0..127 (+ i*128)
    const int schunk = (lane & 7) ^ (lane >> 3); // pre-swizzled source chunk

    f32x4 acc[4][4];
    #pragma unroll
    for (int a = 0; a < 4; ++a)
        #pragma unroll
        for (int b = 0; b < 4; ++b) acc[a][b] = (f32x4){0.f, 0.f, 0.f, 0.f};

    #pragma unroll 1
    for (int kk = 0; kk < NTILE; ++kk) {
        const int k0 = kk * BK;
        __syncthreads();   // previous iteration's reads done
        #pragma unroll
        for (int i = 0; i < 4; ++i) {
            const int row = i * 128 + srow;
            gload_lds16(zb + (size_t)(mbase + row) * C + k0 + schunk * 8,
                        &At[(i * 128 + wid * 8) * BK]);
        }
        gload_lds16(eb + (size_t)(nbase + srow) * C + k0 + schunk * 8,
                    &Bt[(wid * 8) * BK]);
        __syncthreads();   // drains vmcnt (compiler) + barrier

        #pragma unroll
        for (int h = 0; h < 2; ++h) {
            short8 a[4], b[4];
            #pragma unroll
            for (int f = 0; f < 4; ++f) {
                const int ar = wr * 64 + f * 16 + (lane & 15);
                const int ag = h * 4 + (lane >> 4);
                a[f] = *reinterpret_cast<const short8*>(
                    &At[ar * BK + ((ag ^ (ar & 7)) * 8)]);
                const int br = wc * 64 + f * 16 + (lane & 15);
                b[f] = *reinterpret_cast<const short8*>(
                    &Bt[br * BK + ((ag ^ (br & 7)) * 8)]);
            }
            #pragma unroll
            for (int fi = 0; fi < 4; ++fi)
                #pragma unroll
                for (int fj = 0; fj < 4; ++fj)
                    acc[fi][fj] = __builtin_amdgcn_mfma_f32_16x16x32_bf16(
                        a[fi], b[fj], acc[fi][fj], 0, 0, 0);
        }
    }

    // ---- epilogue: per-token top-2 over this block's 128 codes ----
    const int ng0 = nbase + wc * 64 + (lane & 15);
    float hv[4];
    #pragma unroll
    for (int fj = 0; fj < 4; ++fj) hv[fj] = hn[ng0 + fj * 16];

    __syncthreads();                          // all LDS reads done
    float* tl = reinterpret_cast<float*>(smem);  // [512 t][TROW floats] = 72 KB

    const int rg = lane >> 4;          // 0..3 (token sub-row)
    const int g  = (lane & 15) >> 2;   // 0..3 (4-lane code group)

    #pragma unroll
    for (int fi = 0; fi < 4; ++fi) {
        #pragma unroll
        for (int r = 0; r < 4; ++r) {
            float s1 = 3.4e38f, s2 = 3.4e38f;
            int i1 = 0x7fffffff, i2 = 0x7fffffff;
            #pragma unroll
            for (int fj = 0; fj < 4; ++fj) {
                const float sc = hv[fj] - acc[fi][fj][r];
                const int id = ng0 + fj * 16;
                if (lexlt(sc, id, s1, i1)) { s2 = s1; i2 = i1; s1 = sc; i1 = id; }
                else if (lexlt(sc, id, s2, i2)) { s2 = sc; i2 = id; }
            }
            // 2 xor-merge steps: fold 4-lane code group
            #pragma unroll
            for (int off = 1; off <= 2; off <<= 1) {
                const float os1 = __shfl_xor(s1, off), os2 = __shfl_xor(s2, off);
                const int oi1 = __shfl_xor(i1, off), oi2 = __shfl_xor(i2, off);
                merge2(s1, i1, s2, i2, os1, oi1, os2, oi2);
            }
            if ((lane & 3) == 0) {
                const int token = wr * 64 + fi * 16 + rg * 4 + r;
                float* p = &tl[token * TROW + (wc * 4 + g) * 4];
                p[0] = s1; p[1] = __int_as_float(i1);
                p[2] = s2; p[3] = __int_as_float(i2);
            }
        }
    }
    __syncthreads();

    if (tid < BM) {
        const float* p = &tl[tid * TROW];
        float s1 = p[0], s2 = p[2];
        int i1 = __float_as_int(p[1]), i2 = __float_as_int(p[3]);
        #pragma unroll
        for (int e = 1; e < 8; ++e) {
            const float* q = p + e * 4;
            merge2(s1, i1, s2, i2, q[0], __float_as_int(q[1]),
                   q[2], __float_as_int(q[3]));
        }
        const int token = mbase + tid;
        slab[(size_t)token * NSLAB + nb] =
            (float4){s1, __int_as_float(i1), s2, __int_as_float(i2)};
    }
}

__global__ __launch_bounds__(256) void vq_pick(
    const float* __restrict__ z, const float* __restrict__ emb,
    const float4* __restrict__ slab, float* __restrict__ out) {
    const int token = blockIdx.x * 4 + (threadIdx.x >> 6);
    const int lane = threadIdx.x & 63;

    const float4 c = slab[(size_t)token * NSLAB + lane];
    const float cs1 = c.x, cs2 = c.z;
    const int ci1 = __float_as_int(c.y), ci2 = __float_as_int(c.w);

    float bs = cs1;
    int bi = ci1;
    #pragma unroll
    for (int off = 32; off; off >>= 1) {
        const float os = __shfl_xor(bs, off);
        const int oi = __shfl_xor(bi, off);
        if (lexlt(os, oi, bs, bi)) { bs = os; bi = oi; }
    }

    const float tau = 0.25f;   // >> 2*max bf16-rounding score error (~0.07)
    const unsigned long long m1 = __ballot(cs1 <= bs + tau);
    const unsigned long long m2 = __ballot(cs2 <= bs + tau);
    int winner = bi;

    if (__popcll(m1) + __popcll(m2) > 1) {
        const float4 z4 = *reinterpret_cast<const float4*>(
            z + (size_t)token * C + lane * 4);
        float best = 3.4e38f;
        int besti = 0x7fffffff;
        #pragma unroll 1
        for (int pass = 0; pass < 2; ++pass) {
            unsigned long long mm = pass ? m2 : m1;
            while (mm) {
                const int l = __builtin_ctzll(mm);
                mm &= mm - 1;
                const int cidx = __shfl(pass ? ci2 : ci1, l);
                const float4 e4 = *reinterpret_cast<const float4*>(
                    emb + (size_t)cidx * C + lane * 4);
                float p = 0.5f * (e4.x * e4.x + e4.y * e4.y + e4.z * e4.z +
                                  e4.w * e4.w)
                        - (z4.x * e4.x + z4.y * e4.y + z4.z * e4.z + z4.w * e4.w);
                #pragma unroll
                for (int off = 32; off; off >>= 1) p += __shfl_xor(p, off);
                if (lexlt(p, cidx, best, besti)) { best = p; besti = cidx; }
            }
        }
        winner = besti;
    }

    const float4 v = *reinterpret_cast<const float4*>(
        emb + (size_t)winner * C + lane * 4);
    *reinterpret_cast<float4*>(out + (size_t)token * C + lane * 4) = v;
}

extern "C" void kernel_launch(void* const* d_in, const int* in_sizes, int n_in,
                              void* d_out, int out_size, void* d_ws, size_t ws_size,
                              hipStream_t stream) {
    const float* z = (const float*)d_in[0];
    const float* emb = (const float*)d_in[1];
    float* out = (float*)d_out;

    char* w = (char*)d_ws;
    float* hn = (float*)w;            w += (size_t)NCODE * 4;
    ushort* zb = (ushort*)w;          w += (size_t)MTOK * C * 2;
    ushort* eb = (ushort*)w;          w += (size_t)NCODE * C * 2;
    float4* slab = (float4*)w;        // MTOK*NSLAB*16B = 16.8 MB

    vq_norms<<<NCODE, 64, 0, stream>>>(emb, hn);
    vq_cast<<<1024, 256, 0, stream>>>(z, zb, MTOK * C / 4);
    vq_cast<<<512, 256, 0, stream>>>(emb, eb, NCODE * C / 4);

    vq_gemm<<<dim3(MTOK / BM, NCODE / BN), TPB, 0, stream>>>(zb, eb, hn, slab);

    vq_pick<<<MTOK / 4, 256, 0, stream>>>(z, emb, slab, out);
}

// Round 12
// 140.453 us; speedup vs baseline: 7.2678x; 7.2678x over previous
//
#include <hip/hip_runtime.h>

// VQ nearest-codebook via bf16 MFMA GEMM + exact-fp32 rescue.
// score(n,k) = 0.5*|e_k|^2 - z_n.e_k (monotone in squared distance)
//
// Round-12: r10 geometry byte-for-byte (BM=256 BN=128 TPB=512, 48 KB LDS,
// 4096 blocks — best measured, 340 us). Epilogue rebuilt branchless:
// scores -> sortable u64 keys ((monotone(score)<<32)|code), top-2 via
// u64 min/max identity. Exact (score,idx)-lex semantics preserved.
// r11 lesson: acc lives in AGPRs (CSV VGPR_Count excludes it); never set
// min-wave launch_bounds on MFMA kernels.

typedef unsigned short ushort;
typedef unsigned long long u64;
typedef __attribute__((ext_vector_type(8))) short short8;
typedef __attribute__((ext_vector_type(4))) float f32x4;

#define C 256
#define MTOK 16384
#define NCODE 8192
#define BM 256
#define BN 128
#define BK 64
#define TPB 512
#define NSLAB (NCODE / BN)   // 64
#define NTILE (C / BK)       // 4
#define TROWU 18             // u64 per token row in epilogue table (144 B)

__device__ __forceinline__ ushort bf16_rne(float x) {
    unsigned u = __float_as_uint(x);
    return (ushort)((u + 0x7FFFu + ((u >> 16) & 1u)) >> 16);
}

__device__ __forceinline__ bool lexlt(float as, int ai, float bs, int bi) {
    return as < bs || (as == bs && ai < bi);
}

__device__ __forceinline__ u64 mkkey(float sc, int id) {
    const unsigned b = __float_as_uint(sc);
    const unsigned m = ((unsigned)((int)b >> 31)) | 0x80000000u;
    return ((u64)(b ^ m) << 32) | (unsigned)id;
}

__device__ __forceinline__ float keyscore(u64 k) {
    const unsigned u = (unsigned)(k >> 32);
    const unsigned m = ((unsigned)((int)(~u) >> 31)) | 0x80000000u;
    return __uint_as_float(u ^ m);
}

// merge sorted pairs (k1<=k2), (o1<=o2) -> top-2
__device__ __forceinline__ void mergek(u64& k1, u64& k2, u64 o1, u64 o2) {
    const u64 lo = k1 < o1 ? k1 : o1;
    const u64 hi = k1 < o1 ? o1 : k1;
    const u64 m2 = k2 < o2 ? k2 : o2;
    k1 = lo;
    k2 = hi < m2 ? hi : m2;
}

__device__ __forceinline__ void gload_lds16(const ushort* g, ushort* l) {
    __builtin_amdgcn_global_load_lds(
        (const __attribute__((address_space(1))) unsigned int*)g,
        (__attribute__((address_space(3))) unsigned int*)l, 16, 0, 0);
}

__global__ __launch_bounds__(64) void vq_norms(const float* __restrict__ emb,
                                               float* __restrict__ hn) {
    const int k = blockIdx.x;
    const int lane = threadIdx.x;
    const float4 v = *reinterpret_cast<const float4*>(emb + (size_t)k * C + lane * 4);
    float s = v.x * v.x + v.y * v.y + v.z * v.z + v.w * v.w;
    #pragma unroll
    for (int off = 32; off; off >>= 1) s += __shfl_down(s, off);
    if (lane == 0) hn[k] = 0.5f * s;
}

__global__ __launch_bounds__(256) void vq_cast(const float* __restrict__ src,
                                               ushort* __restrict__ dst, int n4) {
    typedef __attribute__((ext_vector_type(4))) ushort us4;
    const float4* s4 = reinterpret_cast<const float4*>(src);
    us4* d4 = reinterpret_cast<us4*>(dst);
    for (int i = blockIdx.x * 256 + threadIdx.x; i < n4; i += gridDim.x * 256) {
        const float4 v = s4[i];
        us4 h;
        h[0] = bf16_rne(v.x);
        h[1] = bf16_rne(v.y);
        h[2] = bf16_rne(v.z);
        h[3] = bf16_rne(v.w);
        d4[i] = h;
    }
}

__global__ __launch_bounds__(TPB) void vq_gemm(
    const ushort* __restrict__ zb, const ushort* __restrict__ eb,
    const float* __restrict__ hn, float4* __restrict__ slab) {
    __shared__ ushort smem[(BM + BN) * BK];   // 48 KB staging
    ushort* At = smem;                         // [256 rows][64 c]
    ushort* Bt = smem + BM * BK;               // [128 rows][64 c]

    const int tid = threadIdx.x;
    const int lane = tid & 63;
    const int wid = __builtin_amdgcn_readfirstlane(tid >> 6);
    const int wr = wid >> 1;          // 0..3 (M quarter)
    const int wc = wid & 1;           // 0..1 (N half)
    const int mbase = blockIdx.x * BM;
    const int nb = blockIdx.y;
    const int nbase = nb * BN;

    // staging: one issue = 512 thr x 16 B = 64 rows; wave covers 8 rows
    const int srow = wid * 8 + (lane >> 3);      // + i*64
    const int schunk = (lane & 7) ^ (lane >> 3); // pre-swizzled source chunk

    f32x4 acc[4][4];
    #pragma unroll
    for (int a = 0; a < 4; ++a)
        #pragma unroll
        for (int b = 0; b < 4; ++b) acc[a][b] = (f32x4){0.f, 0.f, 0.f, 0.f};

    #pragma unroll 1
    for (int kk = 0; kk < NTILE; ++kk) {
        const int k0 = kk * BK;
        __syncthreads();   // previous iteration's reads done
        #pragma unroll
        for (int i = 0; i < 4; ++i) {
            const int row = i * 64 + srow;
            gload_lds16(zb + (size_t)(mbase + row) * C + k0 + schunk * 8,
                        &At[(i * 64 + wid * 8) * BK]);
        }
        #pragma unroll
        for (int i = 0; i < 2; ++i) {
            const int row = i * 64 + srow;
            gload_lds16(eb + (size_t)(nbase + row) * C + k0 + schunk * 8,
                        &Bt[(i * 64 + wid * 8) * BK]);
        }
        __syncthreads();   // drains vmcnt (compiler) + barrier

        #pragma unroll
        for (int h = 0; h < 2; ++h) {
            short8 a[4], b[4];
            #pragma unroll
            for (int f = 0; f < 4; ++f) {
                const int ar = wr * 64 + f * 16 + (lane & 15);
                const int ag = h * 4 + (lane >> 4);
                a[f] = *reinterpret_cast<const short8*>(
                    &At[ar * BK + ((ag ^ (ar & 7)) * 8)]);
                const int br = wc * 64 + f * 16 + (lane & 15);
                b[f] = *reinterpret_cast<const short8*>(
                    &Bt[br * BK + ((ag ^ (br & 7)) * 8)]);
            }
            #pragma unroll
            for (int fi = 0; fi < 4; ++fi)
                #pragma unroll
                for (int fj = 0; fj < 4; ++fj)
                    acc[fi][fj] = __builtin_amdgcn_mfma_f32_16x16x32_bf16(
                        a[fi], b[fj], acc[fi][fj], 0, 0, 0);
        }
    }

    // ---- epilogue: branchless u64-key top-2 over this block's 128 codes ----
    const int ng0 = nbase + wc * 64 + (lane & 15);
    float hv[4];
    #pragma unroll
    for (int fj = 0; fj < 4; ++fj) hv[fj] = hn[ng0 + fj * 16];

    __syncthreads();                          // all LDS reads done
    u64* tl = reinterpret_cast<u64*>(smem);   // [256 t][TROWU u64] = 36 KB

    const int rg = lane >> 4;          // 0..3 (token sub-row)
    const int g  = (lane & 15) >> 2;   // 0..3 (4-lane code group)

    #pragma unroll
    for (int fi = 0; fi < 4; ++fi) {
        #pragma unroll
        for (int r = 0; r < 4; ++r) {
            u64 k1 = ~0ull, k2 = ~0ull;
            #pragma unroll
            for (int fj = 0; fj < 4; ++fj) {
                const u64 key = mkkey(hv[fj] - acc[fi][fj][r], ng0 + fj * 16);
                const bool lt1 = key < k1;
                const bool lt2 = key < k2;
                const u64 nk2 = lt1 ? k1 : (lt2 ? key : k2);
                k1 = lt1 ? key : k1;
                k2 = nk2;
            }
            #pragma unroll
            for (int off = 1; off <= 2; off <<= 1) {
                const u64 o1 = __shfl_xor(k1, off);
                const u64 o2 = __shfl_xor(k2, off);
                mergek(k1, k2, o1, o2);
            }
            if ((lane & 3) == 0) {
                const int token = wr * 64 + fi * 16 + rg * 4 + r;
                u64* p = &tl[token * TROWU + (wc * 4 + g) * 2];
                p[0] = k1;
                p[1] = k2;
            }
        }
    }
    __syncthreads();

    if (tid < BM) {
        const u64* p = &tl[tid * TROWU];
        u64 k1 = p[0], k2 = p[1];
        #pragma unroll
        for (int e = 1; e < 8; ++e)
            mergek(k1, k2, p[e * 2], p[e * 2 + 1]);
        const int token = mbase + tid;
        slab[(size_t)token * NSLAB + nb] =
            (float4){keyscore(k1), __int_as_float((int)(unsigned)k1),
                     keyscore(k2), __int_as_float((int)(unsigned)k2)};
    }
}

__global__ __launch_bounds__(256) void vq_pick(
    const float* __restrict__ z, const float* __restrict__ emb,
    const float4* __restrict__ slab, float* __restrict__ out) {
    const int token = blockIdx.x * 4 + (threadIdx.x >> 6);
    const int lane = threadIdx.x & 63;

    const float4 c = slab[(size_t)token * NSLAB + lane];
    const float cs1 = c.x, cs2 = c.z;
    const int ci1 = __float_as_int(c.y), ci2 = __float_as_int(c.w);

    float bs = cs1;
    int bi = ci1;
    #pragma unroll
    for (int off = 32; off; off >>= 1) {
        const float os = __shfl_xor(bs, off);
        const int oi = __shfl_xor(bi, off);
        if (lexlt(os, oi, bs, bi)) { bs = os; bi = oi; }
    }

    const float tau = 0.25f;   // >> 2*max bf16-rounding score error (~0.07)
    const unsigned long long m1 = __ballot(cs1 <= bs + tau);
    const unsigned long long m2 = __ballot(cs2 <= bs + tau);
    int winner = bi;

    if (__popcll(m1) + __popcll(m2) > 1) {
        const float4 z4 = *reinterpret_cast<const float4*>(
            z + (size_t)token * C + lane * 4);
        float best = 3.4e38f;
        int besti = 0x7fffffff;
        #pragma unroll 1
        for (int pass = 0; pass < 2; ++pass) {
            unsigned long long mm = pass ? m2 : m1;
            while (mm) {
                const int l = __builtin_ctzll(mm);
                mm &= mm - 1;
                const int cidx = __shfl(pass ? ci2 : ci1, l);
                const float4 e4 = *reinterpret_cast<const float4*>(
                    emb + (size_t)cidx * C + lane * 4);
                float p = 0.5f * (e4.x * e4.x + e4.y * e4.y + e4.z * e4.z +
                                  e4.w * e4.w)
                        - (z4.x * e4.x + z4.y * e4.y + z4.z * e4.z + z4.w * e4.w);
                #pragma unroll
                for (int off = 32; off; off >>= 1) p += __shfl_xor(p, off);
                if (lexlt(p, cidx, best, besti)) { best = p; besti = cidx; }
            }
        }
        winner = besti;
    }

    const float4 v = *reinterpret_cast<const float4*>(
        emb + (size_t)winner * C + lane * 4);
    *reinterpret_cast<float4*>(out + (size_t)token * C + lane * 4) = v;
}

extern "C" void kernel_launch(void* const* d_in, const int* in_sizes, int n_in,
                              void* d_out, int out_size, void* d_ws, size_t ws_size,
                              hipStream_t stream) {
    const float* z = (const float*)d_in[0];
    const float* emb = (const float*)d_in[1];
    float* out = (float*)d_out;

    char* w = (char*)d_ws;
    float* hn = (float*)w;            w += (size_t)NCODE * 4;
    ushort* zb = (ushort*)w;          w += (size_t)MTOK * C * 2;
    ushort* eb = (ushort*)w;          w += (size_t)NCODE * C * 2;
    float4* slab = (float4*)w;        // MTOK*NSLAB*16B = 16.8 MB

    vq_norms<<<NCODE, 64, 0, stream>>>(emb, hn);
    vq_cast<<<1024, 256, 0, stream>>>(z, zb, MTOK * C / 4);
    vq_cast<<<512, 256, 0, stream>>>(emb, eb, NCODE * C / 4);

    vq_gemm<<<dim3(MTOK / BM, NCODE / BN), TPB, 0, stream>>>(zb, eb, hn, slab);

    vq_pick<<<MTOK / 4, 256, 0, stream>>>(z, emb, slab, out);
}

// Round 13
// 106.898 us; speedup vs baseline: 9.5492x; 1.3139x over previous
//
#include <hip/hip_runtime.h>

// VQ nearest-codebook via bf16 MFMA GEMM + exact-fp32 rescue.
// score(n,k) = 0.5*|e_k|^2 - z_n.e_k (monotone in squared distance)
//
// Round-13: r12 structure; epilogue keys shrunk u64 -> u32:
//   key = (monotone(score) & 0xFFFFFF80) | local_code_id(7b)
// top-2 = pure umin/umax identity (3 ops/insert, 5 ops/merge, 1 shuffle/key).
// 7-bit score truncation (<=4e-3) absorbed by tau=0.25 rescue window; final
// winner always decided by exact fp32 rescore (lex tie-break preserved).
// Also: vq_norms fused into emb cast (one emb pass, no 8192-block launch).

typedef unsigned short ushort;
typedef unsigned int u32;
typedef unsigned long long u64;
typedef __attribute__((ext_vector_type(8))) short short8;
typedef __attribute__((ext_vector_type(4))) float f32x4;

#define C 256
#define MTOK 16384
#define NCODE 8192
#define BM 256
#define BN 128
#define BK 64
#define TPB 512
#define NSLAB (NCODE / BN)   // 64
#define NTILE (C / BK)       // 4
#define TROW 18              // u32 per token row in epilogue table (72 B)

__device__ __forceinline__ ushort bf16_rne(float x) {
    unsigned u = __float_as_uint(x);
    return (ushort)((u + 0x7FFFu + ((u >> 16) & 1u)) >> 16);
}

__device__ __forceinline__ bool lexlt(float as, int ai, float bs, int bi) {
    return as < bs || (as == bs && ai < bi);
}

__device__ __forceinline__ u32 mono32(float sc) {
    const u32 b = __float_as_uint(sc);
    return b ^ (((u32)((int)b >> 31)) | 0x80000000u);
}

__device__ __forceinline__ float unmono32(u32 u) {
    const u32 m = ((u32)((int)(~u) >> 31)) | 0x80000000u;
    return __uint_as_float(u ^ m);
}

// insert key into sorted top-2 (k1<=k2): 3 ops, branchless
__device__ __forceinline__ void ins2(u32& k1, u32& k2, u32 key) {
    k2 = min(k2, max(k1, key));
    k1 = min(k1, key);
}

__device__ __forceinline__ void gload_lds16(const ushort* g, ushort* l) {
    __builtin_amdgcn_global_load_lds(
        (const __attribute__((address_space(1))) unsigned int*)g,
        (__attribute__((address_space(3))) unsigned int*)l, 16, 0, 0);
}

// fused: emb -> bf16 cast + half-norms (one pass over emb)
__global__ __launch_bounds__(256) void vq_ecast(const float* __restrict__ emb,
                                                ushort* __restrict__ eb,
                                                float* __restrict__ hn) {
    typedef __attribute__((ext_vector_type(4))) ushort us4;
    const int lane = threadIdx.x & 63;
    const int wid = threadIdx.x >> 6;
    const int row0 = blockIdx.x * 16 + wid * 4;
    #pragma unroll
    for (int j = 0; j < 4; ++j) {
        const int k = row0 + j;
        const float4 v = *reinterpret_cast<const float4*>(
            emb + (size_t)k * C + lane * 4);
        us4 h;
        h[0] = bf16_rne(v.x);
        h[1] = bf16_rne(v.y);
        h[2] = bf16_rne(v.z);
        h[3] = bf16_rne(v.w);
        *reinterpret_cast<us4*>(eb + (size_t)k * C + lane * 4) = h;
        float s = v.x * v.x + v.y * v.y + v.z * v.z + v.w * v.w;
        #pragma unroll
        for (int off = 32; off; off >>= 1) s += __shfl_down(s, off);
        if (lane == 0) hn[k] = 0.5f * s;
    }
}

__global__ __launch_bounds__(256) void vq_cast(const float* __restrict__ src,
                                               ushort* __restrict__ dst, int n4) {
    typedef __attribute__((ext_vector_type(4))) ushort us4;
    const float4* s4 = reinterpret_cast<const float4*>(src);
    us4* d4 = reinterpret_cast<us4*>(dst);
    for (int i = blockIdx.x * 256 + threadIdx.x; i < n4; i += gridDim.x * 256) {
        const float4 v = s4[i];
        us4 h;
        h[0] = bf16_rne(v.x);
        h[1] = bf16_rne(v.y);
        h[2] = bf16_rne(v.z);
        h[3] = bf16_rne(v.w);
        d4[i] = h;
    }
}

__global__ __launch_bounds__(TPB) void vq_gemm(
    const ushort* __restrict__ zb, const ushort* __restrict__ eb,
    const float* __restrict__ hn, float4* __restrict__ slab) {
    __shared__ ushort smem[(BM + BN) * BK];   // 48 KB staging
    ushort* At = smem;                         // [256 rows][64 c]
    ushort* Bt = smem + BM * BK;               // [128 rows][64 c]

    const int tid = threadIdx.x;
    const int lane = tid & 63;
    const int wid = __builtin_amdgcn_readfirstlane(tid >> 6);
    const int wr = wid >> 1;          // 0..3 (M quarter)
    const int wc = wid & 1;           // 0..1 (N half)
    const int mbase = blockIdx.x * BM;
    const int nb = blockIdx.y;
    const int nbase = nb * BN;

    // staging: one issue = 512 thr x 16 B = 64 rows; wave covers 8 rows
    const int srow = wid * 8 + (lane >> 3);      // + i*64
    const int schunk = (lane & 7) ^ (lane >> 3); // pre-swizzled source chunk

    f32x4 acc[4][4];
    #pragma unroll
    for (int a = 0; a < 4; ++a)
        #pragma unroll
        for (int b = 0; b < 4; ++b) acc[a][b] = (f32x4){0.f, 0.f, 0.f, 0.f};

    #pragma unroll 1
    for (int kk = 0; kk < NTILE; ++kk) {
        const int k0 = kk * BK;
        __syncthreads();   // previous iteration's reads done
        #pragma unroll
        for (int i = 0; i < 4; ++i) {
            const int row = i * 64 + srow;
            gload_lds16(zb + (size_t)(mbase + row) * C + k0 + schunk * 8,
                        &At[(i * 64 + wid * 8) * BK]);
        }
        #pragma unroll
        for (int i = 0; i < 2; ++i) {
            const int row = i * 64 + srow;
            gload_lds16(eb + (size_t)(nbase + row) * C + k0 + schunk * 8,
                        &Bt[(i * 64 + wid * 8) * BK]);
        }
        __syncthreads();   // drains vmcnt (compiler) + barrier

        #pragma unroll
        for (int h = 0; h < 2; ++h) {
            short8 a[4], b[4];
            #pragma unroll
            for (int f = 0; f < 4; ++f) {
                const int ar = wr * 64 + f * 16 + (lane & 15);
                const int ag = h * 4 + (lane >> 4);
                a[f] = *reinterpret_cast<const short8*>(
                    &At[ar * BK + ((ag ^ (ar & 7)) * 8)]);
                const int br = wc * 64 + f * 16 + (lane & 15);
                b[f] = *reinterpret_cast<const short8*>(
                    &Bt[br * BK + ((ag ^ (br & 7)) * 8)]);
            }
            #pragma unroll
            for (int fi = 0; fi < 4; ++fi)
                #pragma unroll
                for (int fj = 0; fj < 4; ++fj)
                    acc[fi][fj] = __builtin_amdgcn_mfma_f32_16x16x32_bf16(
                        a[fi], b[fj], acc[fi][fj], 0, 0, 0);
        }
    }

    // ---- epilogue: u32-key top-2 over this block's 128 codes ----
    const int lid0 = wc * 64 + (lane & 15);   // local code id of fj=0 (7 bits)
    float hv[4];
    #pragma unroll
    for (int fj = 0; fj < 4; ++fj) hv[fj] = hn[nbase + lid0 + fj * 16];

    __syncthreads();                          // all LDS reads done
    u32* tl = reinterpret_cast<u32*>(smem);   // [256 t][TROW u32] = 18 KB

    const int rg = lane >> 4;          // 0..3 (token sub-row)
    const int g  = (lane & 15) >> 2;   // 0..3 (4-lane code group)

    #pragma unroll
    for (int fi = 0; fi < 4; ++fi) {
        #pragma unroll
        for (int r = 0; r < 4; ++r) {
            u32 k1 = 0xFFFFFFFFu, k2 = 0xFFFFFFFFu;
            #pragma unroll
            for (int fj = 0; fj < 4; ++fj) {
                const u32 key = (mono32(hv[fj] - acc[fi][fj][r]) & 0xFFFFFF80u)
                              | (u32)(lid0 + fj * 16);
                ins2(k1, k2, key);
            }
            #pragma unroll
            for (int off = 1; off <= 2; off <<= 1) {
                const u32 o1 = __shfl_xor(k1, off);
                const u32 o2 = __shfl_xor(k2, off);
                const u32 lo = min(k1, o1);
                const u32 hi = max(k1, o1);
                k2 = min(hi, min(k2, o2));
                k1 = lo;
            }
            if ((lane & 3) == 0) {
                const int token = wr * 64 + fi * 16 + rg * 4 + r;
                *reinterpret_cast<u64*>(&tl[token * TROW + (wc * 4 + g) * 2]) =
                    ((u64)k2 << 32) | k1;
            }
        }
    }
    __syncthreads();

    if (tid < BM) {
        const u64* p = reinterpret_cast<const u64*>(&tl[tid * TROW]);
        u32 k1 = 0xFFFFFFFFu, k2 = 0xFFFFFFFFu;
        #pragma unroll
        for (int e = 0; e < 8; ++e) {
            const u64 v = p[e];
            ins2(k1, k2, (u32)v);
            ins2(k1, k2, (u32)(v >> 32));
        }
        const int token = mbase + tid;
        slab[(size_t)token * NSLAB + nb] =
            (float4){unmono32(k1 & 0xFFFFFF80u),
                     __int_as_float(nbase + (int)(k1 & 0x7Fu)),
                     unmono32(k2 & 0xFFFFFF80u),
                     __int_as_float(nbase + (int)(k2 & 0x7Fu))};
    }
}

__global__ __launch_bounds__(256) void vq_pick(
    const float* __restrict__ z, const float* __restrict__ emb,
    const float4* __restrict__ slab, float* __restrict__ out) {
    const int token = blockIdx.x * 4 + (threadIdx.x >> 6);
    const int lane = threadIdx.x & 63;

    const float4 c = slab[(size_t)token * NSLAB + lane];
    const float cs1 = c.x, cs2 = c.z;
    const int ci1 = __float_as_int(c.y), ci2 = __float_as_int(c.w);

    float bs = cs1;
    int bi = ci1;
    #pragma unroll
    for (int off = 32; off; off >>= 1) {
        const float os = __shfl_xor(bs, off);
        const int oi = __shfl_xor(bi, off);
        if (lexlt(os, oi, bs, bi)) { bs = os; bi = oi; }
    }

    const float tau = 0.25f;   // >> 2*(bf16 eps ~0.035) + key truncation 4e-3
    const unsigned long long m1 = __ballot(cs1 <= bs + tau);
    const unsigned long long m2 = __ballot(cs2 <= bs + tau);
    int winner = bi;

    if (__popcll(m1) + __popcll(m2) > 1) {
        const float4 z4 = *reinterpret_cast<const float4*>(
            z + (size_t)token * C + lane * 4);
        float best = 3.4e38f;
        int besti = 0x7fffffff;
        #pragma unroll 1
        for (int pass = 0; pass < 2; ++pass) {
            unsigned long long mm = pass ? m2 : m1;
            while (mm) {
                const int l = __builtin_ctzll(mm);
                mm &= mm - 1;
                const int cidx = __shfl(pass ? ci2 : ci1, l);
                const float4 e4 = *reinterpret_cast<const float4*>(
                    emb + (size_t)cidx * C + lane * 4);
                float p = 0.5f * (e4.x * e4.x + e4.y * e4.y + e4.z * e4.z +
                                  e4.w * e4.w)
                        - (z4.x * e4.x + z4.y * e4.y + z4.z * e4.z + z4.w * e4.w);
                #pragma unroll
                for (int off = 32; off; off >>= 1) p += __shfl_xor(p, off);
                if (lexlt(p, cidx, best, besti)) { best = p; besti = cidx; }
            }
        }
        winner = besti;
    }

    const float4 v = *reinterpret_cast<const float4*>(
        emb + (size_t)winner * C + lane * 4);
    *reinterpret_cast<float4*>(out + (size_t)token * C + lane * 4) = v;
}

extern "C" void kernel_launch(void* const* d_in, const int* in_sizes, int n_in,
                              void* d_out, int out_size, void* d_ws, size_t ws_size,
                              hipStream_t stream) {
    const float* z = (const float*)d_in[0];
    const float* emb = (const float*)d_in[1];
    float* out = (float*)d_out;

    char* w = (char*)d_ws;
    float* hn = (float*)w;            w += (size_t)NCODE * 4;
    ushort* zb = (ushort*)w;          w += (size_t)MTOK * C * 2;
    ushort* eb = (ushort*)w;          w += (size_t)NCODE * C * 2;
    float4* slab = (float4*)w;        // MTOK*NSLAB*16B = 16.8 MB

    vq_ecast<<<NCODE / 16, 256, 0, stream>>>(emb, eb, hn);
    vq_cast<<<1024, 256, 0, stream>>>(z, zb, MTOK * C / 4);

    vq_gemm<<<dim3(MTOK / BM, NCODE / BN), TPB, 0, stream>>>(zb, eb, hn, slab);

    vq_pick<<<MTOK / 4, 256, 0, stream>>>(z, emb, slab, out);
}